// Round 7
// baseline (160.821 us; speedup 1.0000x reference)
//
#include <hip/hip_runtime.h>

// ROI max pooling, matching the JAX reference:
//   img:  (1, 200, 200, 512) fp32, NHWC
//   rois: (1, 128, 4) fp32 as (x, y, w, h) in feature-map pixels
//   pool: 7
// out: (1, 128, 7, 7, 512) fp32
//
// Bin boundaries replicate  int(x + k*(w/P))  in strict IEEE fp32
// (separate div/mul/add, no FMA contraction) so the integer pixel ranges
// match the reference exactly; the max over identical pixel sets is then
// bitwise identical.
//
// R9: R8's Morton + equal-area-XCD schedule (FETCH 143->98 MB proven),
// but the in-block prologue moves from 512-threads/8-barriers (~13-15us
// aggregate, VALUBusy 52%) to ONE WAVE + shuffles + 1 barrier:
//   - 2 ROIs per lane, Morton rank via 64-step __shfl all-to-all
//   - area prefix via two 64-wide shuffle scans (no LDS ranking loops
//     -> kills the 451k bank-conflict cycles too)
//   - chunk counts via __ballot/__popcll, spill/free prefixes via
//     8-lane shuffle scan
//   - closed-form slot->(roi,bin) inverse, identical math to R8 (proven)
// Waves 1-7 idle at the barrier (no issue pressure); with 4 blocks/CU the
// other blocks' memory phases keep the CU's miss queues saturated, so the
// ~1us prologue hides under memory latency. Deterministic across blocks
// (same fp ops, same inputs; area margins >> ulp) -> same bijection
// everywhere -> bitwise-identical output.

#define IMG_H 200
#define IMG_W 200
#define IMG_C 512
#define C4 (IMG_C / 4)   // 128 float4 slots per pixel
#define POOL 7
#define NROI 128
#define PLANES 4         // pixel-lanes per block
#define NXCD 8
#define NBIN (POOL * POOL)
#define NITEM (NROI * NBIN)            // 6272
#define SLOTS_PER_XCD (NITEM / NXCD)   // 784

typedef float f4v __attribute__((ext_vector_type(4)));

__device__ __forceinline__ float4 max4(float4 a, float4 b) {
    return make_float4(fmaxf(a.x, b.x), fmaxf(a.y, b.y),
                       fmaxf(a.z, b.z), fmaxf(a.w, b.w));
}

__device__ __forceinline__ int imin(int a, int b) { return a < b ? a : b; }
__device__ __forceinline__ int imax(int a, int b) { return a > b ? a : b; }

// spread low 8 bits: b7..b0 -> 0b0b0b0b (Morton helper)
__device__ __forceinline__ unsigned spread8(unsigned x) {
    x &= 0xFFu;
    x = (x | (x << 4)) & 0x0F0Fu;
    x = (x | (x << 2)) & 0x3333u;
    x = (x | (x << 1)) & 0x5555u;
    return x;
}

__global__ __launch_bounds__(PLANES * 128, 8) void roi_pool_kernel(
    const float* __restrict__ img,
    const float* __restrict__ rois,
    float* __restrict__ out)
{
    __shared__ int    s_perm[NROI];        // rank -> roi
    __shared__ float  s_area[NROI];        // by rank
    __shared__ int    s_len[NXCD];         // items in chunk
    __shared__ int    s_rstart[NXCD];      // first rank of chunk
    __shared__ int    s_spillpre[NXCD + 1];
    __shared__ int    s_freepre[NXCD + 1];
    __shared__ int    s_roi, s_bin;
    __shared__ float4 red[PLANES - 1][C4];

    const int tid = threadIdx.x;

    if (tid < 64) {                        // wave 0 only — ~1us, reg/shuffle
        const int lane = tid;
        const float4* __restrict__ rois4 = (const float4*)rois;
        const float4 ra = rois4[lane];          // roi = lane      (x,y,w,h)
        const float4 rb = rois4[lane + 64];     // roi = lane + 64

        // Morton keys of ROI centers (same arithmetic as R8)
        const unsigned cxa = (unsigned)(int)(ra.x + 0.5f * ra.z);
        const unsigned cya = (unsigned)(int)(ra.y + 0.5f * ra.w);
        const unsigned cxb = (unsigned)(int)(rb.x + 0.5f * rb.z);
        const unsigned cyb = (unsigned)(int)(rb.y + 0.5f * rb.w);
        const int keyA = (int)((spread8(cya) << 1) | spread8(cxa));
        const int keyB = (int)((spread8(cyb) << 1) | spread8(cxb));

        // all-to-all rank via shuffles; tie-break by roi index.
        // keyA's roi = lane (<64); keyB's roi = lane+64 (>=64).
        int rankA = 0, rankB = 0;
        for (int d = 0; d < 64; ++d) {
            const int oA = __shfl(keyA, d);   // key of roi d       (<64)
            const int oB = __shfl(keyB, d);   // key of roi d+64    (>=64)
            rankA += (int)((oA < keyA) | ((oA == keyA) & (d < lane)));
            rankA += (int)(oB < keyA);        // d+64 < lane is always false
            rankB += (int)(oA <= keyB);       // d < lane+64 is always true
            rankB += (int)((oB < keyB) | ((oB == keyB) & (d < lane)));
        }
        s_perm[rankA] = lane;
        s_perm[rankB] = lane + 64;
        s_area[rankA] = ra.z * ra.w;
        s_area[rankB] = rb.z * rb.w;
        __threadfence_block();               // scatter -> gather (same wave)

        // area by rank; inclusive prefix via two 64-wide shuffle scans
        const float aLo = s_area[lane];
        const float aHi = s_area[lane + 64];
        float pLo = aLo;
        #pragma unroll
        for (int d = 1; d < 64; d <<= 1) {
            const float o = __shfl_up(pLo, d);
            if (lane >= d) pLo += o;
        }
        const float totLo = __shfl(pLo, 63);
        float pHi = aHi;
        #pragma unroll
        for (int d = 1; d < 64; d <<= 1) {
            const float o = __shfl_up(pHi, d);
            if (lane >= d) pHi += o;
        }
        pHi += totLo;
        const float total = __shfl(pHi, 63);

        // equal-area chunk id at ROI midpoint (monotone in rank:
        // mid(r+1)-mid(r) = 0.5*(a_r + a_{r+1}) >= 64 >> fp32 ulp)
        const float scale = (float)NXCD / total;
        const int cLo = imin((int)((pLo - 0.5f * aLo) * scale), NXCD - 1);
        const int cHi = imin((int)((pHi - 0.5f * aHi) * scale), NXCD - 1);

        // per-chunk ROI counts + prefix, via ballots (uniform results)
        int myCnt = 0, myPre = 0;
        #pragma unroll
        for (int c = 0; c < NXCD; ++c) {
            const int n = __popcll(__ballot(cLo == c)) +
                          __popcll(__ballot(cHi == c));
            if (lane == c) myCnt = n;
            if (lane >  c) myPre += n;     // ROIs in chunks before 'lane'
        }
        const int myLen = myCnt * NBIN;
        int ov = imax(myLen - SLOTS_PER_XCD, 0);
        int fr = imax(SLOTS_PER_XCD - myLen, 0);
        int ovI = ov, frI = fr;            // inclusive scans over 8 lanes
        #pragma unroll
        for (int d = 1; d < 8; d <<= 1) {
            const int o = __shfl_up(ovI, d);
            const int f = __shfl_up(frI, d);
            if (lane >= d) { ovI += o; frI += f; }
        }
        if (lane < NXCD) {
            s_len[lane]      = myLen;
            s_rstart[lane]   = myPre;
            s_spillpre[lane] = ovI - ov;   // exclusive
            s_freepre[lane]  = frI - fr;
        }
        if (lane == NXCD - 1) { s_spillpre[NXCD] = ovI; s_freepre[NXCD] = frI; }
        __threadfence_block();

        // closed-form inverse: slot blockIdx.x -> (roi, bin). Identical
        // math to R8 (validated, absmax 0.0): slot j*8+x is chunk x's
        // j-th item if j < len[x], else the (freepre[x]+(j-len[x]))-th
        // global free slot, filled by spill si from chunk xx with
        // spillpre[xx] <= si < spillpre[xx+1], item 784+(si-spillpre[xx]).
        if (lane == 0) {
            const int x = blockIdx.x & (NXCD - 1);
            const int j = blockIdx.x >> 3;
            int tt, mm;
            const int lenx = s_len[x];
            if (j < lenx) {
                tt = s_rstart[x] + j / NBIN;
                mm = j % NBIN;
            } else {
                const int si = s_freepre[x] + (j - lenx);
                int xx = 0;
                while (!(si >= s_spillpre[xx] && si < s_spillpre[xx + 1])) ++xx;
                const int jj = SLOTS_PER_XCD + (si - s_spillpre[xx]);
                tt = s_rstart[xx] + jj / NBIN;
                mm = jj % NBIN;
            }
            s_roi = s_perm[tt];
            s_bin = mm;
        }
    }
    __syncthreads();                                           // B1 (only)

    const int roi = s_roi;
    const int bin = s_bin;
    const int jy = bin / POOL;
    const int ix = bin % POOL;

    const float rx = rois[roi * 4 + 0];
    const float ry = rois[roi * 4 + 1];
    const float rw = rois[roi * 4 + 2];
    const float rh = rois[roi * 4 + 3];

    // Strict fp32, no contraction: s = w/P; b[k] = int(x + k*s)
    const float sx = __fdiv_rn(rw, 7.0f);
    const float sy = __fdiv_rn(rh, 7.0f);
    const int x1 = (int)__fadd_rn(rx, __fmul_rn((float)ix,       sx));
    const int x2 = (int)__fadd_rn(rx, __fmul_rn((float)(ix + 1), sx));
    const int y1 = (int)__fadd_rn(ry, __fmul_rn((float)jy,       sy));
    const int y2 = (int)__fadd_rn(ry, __fmul_rn((float)(jy + 1), sy));

    const int c4 = tid & 127;               // channel quad
    const int p  = tid >> 7;                // pixel-lane 0..3
    const float4* __restrict__ img4 = (const float4*)img;

    const int bw = x2 - x1;                 // >= 1 by problem construction
    const int area = bw * (y2 - y1);

    const float4 NEG = make_float4(-INFINITY, -INFINITY, -INFINITY, -INFINITY);
    float4 m = NEG;

    // Lane p handles linearized bin pixels p, p+4, p+8, ... (row-major in bin).
    int dx = p, dy = 0;
    while (dx >= bw) { dx -= bw; ++dy; }    // p<4, cheap init
    #pragma unroll 2
    for (int i = p; i < area; i += PLANES) {
        const size_t px = (size_t)(y1 + dy) * IMG_W + (size_t)(x1 + dx);
        m = max4(m, img4[px * C4 + c4]);
        dx += PLANES;
        while (dx >= bw) { dx -= bw; ++dy; }
    }

    // Cross-lane (p) reduction via LDS; lanes with no pixels hold -INF.
    if (p > 0) red[p - 1][c4] = m;
    __syncthreads();                                           // B2
    if (p == 0) {
        m = max4(m, red[0][c4]);
        m = max4(m, red[1][c4]);
        m = max4(m, red[2][c4]);

        float4* __restrict__ out4 = (float4*)out;
        f4v* __restrict__ dst =
            (f4v*)&out4[((size_t)(roi * POOL + jy) * POOL + ix) * C4 + c4];
        __builtin_nontemporal_store(*(const f4v*)&m, dst);
    }
}

extern "C" void kernel_launch(void* const* d_in, const int* in_sizes, int n_in,
                              void* d_out, int out_size, void* d_ws, size_t ws_size,
                              hipStream_t stream) {
    (void)in_sizes; (void)n_in; (void)d_ws; (void)ws_size; (void)out_size;
    const float* img  = (const float*)d_in[0];
    const float* rois = (const float*)d_in[1];
    // d_in[2] is pool_size (=7), hardcoded.
    float* out = (float*)d_out;

    roi_pool_kernel<<<dim3(NITEM), dim3(PLANES * 128), 0, stream>>>(
        img, rois, out);
}

// Round 8
// 156.221 us; speedup vs baseline: 1.0294x; 1.0294x over previous
//
#include <hip/hip_runtime.h>

// ROI max pooling, matching the JAX reference:
//   img:  (1, 200, 200, 512) fp32, NHWC
//   rois: (1, 128, 4) fp32 as (x, y, w, h) in feature-map pixels
//   pool: 7
// out: (1, 128, 7, 7, 512) fp32
//
// Bin boundaries replicate  int(x + k*(w/P))  in strict IEEE fp32
// (separate div/mul/add, no FMA contraction) so the integer pixel ranges
// match the reference exactly; the max over identical pixel sets is then
// bitwise identical.
//
// R10: amortize the schedule. Ledger across R5/R8/R9: scheduled variants'
// extra VALU-busy time (18/23/17us) ≈ their gap to a ~33-37us scheduled
// memory phase -> the Morton+equal-area schedule DOES convert FETCH
// 143->98MB into time, but the per-block prologue (~0.94us/block) ate it
// at 6272 blocks. Fix: block = (roi, jy) = 7 x-bins -> grid 896, prologue
// aggregate 23 -> ~3.3us. Prologue is R8's (validated, absmax 0.0) with
// items-per-ROI = 7. Memory loop = R4's per-bin rect loop, ix fully
// unrolled into m[7] accumulators (static indexing), ONE LDS reduce.

#define IMG_H 200
#define IMG_W 200
#define IMG_C 512
#define C4 (IMG_C / 4)   // 128 float4 slots per pixel
#define POOL 7
#define NROI 128
#define NXCD 8
#define JPB  POOL                      // items per ROI = 7 (one per jy)
#define NBLK (NROI * JPB)              // 896 blocks
#define SLOTS_PER_XCD (NBLK / NXCD)    // 112

typedef float f4v __attribute__((ext_vector_type(4)));

__device__ __forceinline__ float4 max4(float4 a, float4 b) {
    return make_float4(fmaxf(a.x, b.x), fmaxf(a.y, b.y),
                       fmaxf(a.z, b.z), fmaxf(a.w, b.w));
}

__device__ __forceinline__ int imin(int a, int b) { return a < b ? a : b; }
__device__ __forceinline__ int imax(int a, int b) { return a > b ? a : b; }

// spread low 8 bits: b7..b0 -> 0b0b0b0b (Morton helper)
__device__ __forceinline__ unsigned spread8(unsigned x) {
    x &= 0xFFu;
    x = (x | (x << 4)) & 0x0F0Fu;
    x = (x | (x << 2)) & 0x3333u;
    x = (x | (x << 1)) & 0x5555u;
    return x;
}

__global__ __launch_bounds__(512, 4) void roi_pool_kernel(
    const float* __restrict__ img,
    const float* __restrict__ rois,
    float* __restrict__ out)
{
    // ---- schedule scratch (R8's, ~3.4 KB) + reduction buffer (42 KB) ----
    __shared__ unsigned short s_key[NROI];
    __shared__ float          s_areaROI[NROI];
    __shared__ int            s_rank[NROI];
    __shared__ unsigned char  s_perm[NROI];
    __shared__ float          s_area[NROI];
    __shared__ float          s_pref[NROI];
    __shared__ int            s_chunk[NROI];
    __shared__ int            s_rstart[NXCD];
    __shared__ int            s_len[NXCD];
    __shared__ int            s_spillpre[NXCD + 1];
    __shared__ int            s_freepre[NXCD + 1];
    __shared__ int            s_roi, s_jy;
    __shared__ float4         red[3][POOL][C4];   // 3*7*128*16B = 42 KB

    const int tid = threadIdx.x;
    const int t   = tid & 127;            // ROI / rank lane
    const int seg = tid >> 7;             // 0..3

    if (seg == 0) {
        const float rx = rois[t * 4 + 0];
        const float ry = rois[t * 4 + 1];
        const float rw = rois[t * 4 + 2];
        const float rh = rois[t * 4 + 3];
        const unsigned cx = (unsigned)(int)(rx + 0.5f * rw);   // 0..199
        const unsigned cy = (unsigned)(int)(ry + 0.5f * rh);
        s_key[t] = (unsigned short)((spread8(cy) << 1) | spread8(cx));
        s_areaROI[t] = rw * rh;
        s_rank[t] = 0;
    }
    if (tid < NXCD) s_len[tid] = 0;
    __syncthreads();                                           // B1

    // 4-way split ranking: tid ranks ROI t against keys [seg*32, seg*32+32)
    {
        const unsigned my = s_key[t];
        int r = 0;
        const int u0 = seg * 32;
        #pragma unroll 8
        for (int u = u0; u < u0 + 32; ++u) {
            const unsigned ku = s_key[u];
            r += (int)((ku < my) | ((ku == my) & (u < t)));
        }
        atomicAdd(&s_rank[t], r);
    }
    __syncthreads();                                           // B2

    if (seg == 0) {
        const int r = s_rank[t];
        s_perm[r] = (unsigned char)t;
        s_area[r] = s_areaROI[t];
    }
    __syncthreads();                                           // B3

    // inclusive area scan by rank: shuffle scan within each of 2 waves.
    if (seg == 0) {
        float v = s_area[t];
        #pragma unroll
        for (int d = 1; d < 64; d <<= 1) {
            const float o = __shfl_up(v, d);
            if ((t & 63) >= d) v += o;
        }
        s_pref[t] = v;                     // wave-local inclusive
    }
    __syncthreads();                                           // B4

    if (seg == 0) {
        const float w0tot = s_pref[63];
        const float pre   = s_pref[t] + ((t >= 64) ? w0tot : 0.f);
        const float total = s_pref[127] + w0tot;
        const float mid = pre - 0.5f * s_area[t];
        const int c = imin((int)(mid * ((float)NXCD / total)), NXCD - 1);
        s_chunk[t] = c;
        atomicAdd(&s_len[c], JPB);
    }
    __syncthreads();                                           // B5

    if (seg == 0) {
        const int c = s_chunk[t];
        if (t == 0 || s_chunk[t - 1] != c) s_rstart[c] = t;
    }
    if (tid == 0) {
        int sp = 0, fp = 0;
        #pragma unroll
        for (int x = 0; x < NXCD; ++x) {
            s_spillpre[x] = sp;
            s_freepre[x]  = fp;
            sp += imax(0, s_len[x] - SLOTS_PER_XCD);
            fp += imax(0, SLOTS_PER_XCD - s_len[x]);
        }
        s_spillpre[NXCD] = sp;
        s_freepre[NXCD]  = fp;
    }
    __syncthreads();                                           // B6

    // closed-form inverse: slot blockIdx.x -> (roi, jy). R8's validated
    // logic with items-per-ROI = 7.
    if (tid == 0) {
        const int x = blockIdx.x & (NXCD - 1);
        const int j = blockIdx.x >> 3;
        int tt, mm;
        const int lenx = s_len[x];
        if (j < lenx) {
            tt = s_rstart[x] + j / JPB;
            mm = j % JPB;
        } else {
            const int si = s_freepre[x] + (j - lenx);
            int xx = 0;
            while (!(si >= s_spillpre[xx] && si < s_spillpre[xx + 1])) ++xx;
            const int jj = SLOTS_PER_XCD + (si - s_spillpre[xx]);
            tt = s_rstart[xx] + jj / JPB;
            mm = jj % JPB;
        }
        s_roi = (int)s_perm[tt];
        s_jy  = mm;
    }
    __syncthreads();                                           // B7

    const int roi = s_roi;
    const int jy  = s_jy;

    const float rx = rois[roi * 4 + 0];
    const float ry = rois[roi * 4 + 1];
    const float rw = rois[roi * 4 + 2];
    const float rh = rois[roi * 4 + 3];

    // Strict fp32, no contraction: s = w/P; b[k] = int(x + k*s)
    const float sx = __fdiv_rn(rw, 7.0f);
    const float sy = __fdiv_rn(rh, 7.0f);
    const int y1 = (int)__fadd_rn(ry, __fmul_rn((float)jy,       sy));
    const int y2 = (int)__fadd_rn(ry, __fmul_rn((float)(jy + 1), sy));

    const int c4 = tid & 127;               // channel quad
    const int p  = tid >> 7;                // row-lane 0..3
    const float4* __restrict__ img4 = (const float4*)img;

    const float4 NEG = make_float4(-INFINITY, -INFINITY, -INFINITY, -INFINITY);
    float4 m[POOL];

    // 7 x-bins of this (roi, jy) row, fully unrolled (static m[] index).
    // p splits rows p-strided; per-bin rect loop is R4's proven pattern.
    #pragma unroll
    for (int ix = 0; ix < POOL; ++ix) {
        const int x1 = (int)__fadd_rn(rx, __fmul_rn((float)ix,       sx));
        const int x2 = (int)__fadd_rn(rx, __fmul_rn((float)(ix + 1), sx));
        float4 acc = NEG;
        for (int yy = y1 + p; yy < y2; yy += 4) {
            const float4* __restrict__ row = img4 + ((size_t)yy * IMG_W) * C4 + c4;
            #pragma unroll 4
            for (int x = x1; x < x2; ++x)
                acc = max4(acc, row[(size_t)x * C4]);
        }
        m[ix] = acc;
    }

    // single cross-p reduce for all 7 bins
    if (p > 0) {
        #pragma unroll
        for (int ix = 0; ix < POOL; ++ix) red[p - 1][ix][c4] = m[ix];
    }
    __syncthreads();                                           // B8
    if (p == 0) {
        float4* __restrict__ out4 = (float4*)out;
        #pragma unroll
        for (int ix = 0; ix < POOL; ++ix) {
            float4 mm = max4(max4(m[ix], red[0][ix][c4]),
                             max4(red[1][ix][c4], red[2][ix][c4]));
            f4v* __restrict__ dst =
                (f4v*)&out4[((size_t)(roi * POOL + jy) * POOL + ix) * C4 + c4];
            __builtin_nontemporal_store(*(const f4v*)&mm, dst);
        }
    }
}

extern "C" void kernel_launch(void* const* d_in, const int* in_sizes, int n_in,
                              void* d_out, int out_size, void* d_ws, size_t ws_size,
                              hipStream_t stream) {
    (void)in_sizes; (void)n_in; (void)d_ws; (void)ws_size; (void)out_size;
    const float* img  = (const float*)d_in[0];
    const float* rois = (const float*)d_in[1];
    // d_in[2] is pool_size (=7), hardcoded.
    float* out = (float*)d_out;

    roi_pool_kernel<<<dim3(NBLK), dim3(512), 0, stream>>>(img, rois, out);
}

// Round 9
// 141.430 us; speedup vs baseline: 1.1371x; 1.1046x over previous
//
#include <hip/hip_runtime.h>

// ROI max pooling, matching the JAX reference:
//   img:  (1, 200, 200, 512) fp32, NHWC
//   rois: (1, 128, 4) fp32 as (x, y, w, h) in feature-map pixels
//   pool: 7
// out: (1, 128, 7, 7, 512) fp32
//
// Bin boundaries replicate  int(x + k*(w/P))  in strict IEEE fp32
// (separate div/mul/add, no FMA contraction) so the integer pixel ranges
// match the reference exactly; the max over identical pixel sets is then
// bitwise identical.
//
// R11 = revert to R4 (best measured: bench 140.2us, kernel ~48us).
// Ledger across R2-R10: delivered read throughput is ~26-27 GB/s/CU
// invariant under ILP x4 (R3), wave count x4 (R4), occupancy 33-67%
// (R10 vs R8), and FETCH -31% via Morton+XCD scheduling (R8) -> the
// kernel sits on a flat per-CU read-path cap for this scattered-
// rectangle float4 stream, not on latency, occupancy, or HBM bytes.
// Structural floor: 340 MB logical / (256 CU x 26.6 GB/s) ~= 48 us =
// this kernel. Schedule variants (R5/R8/R9/R10) all paid a prologue/
// granularity cost >= 0 gain; image-centric dedup (atomic CAS-max)
// sizes to ~138us. This decomposition is the roofline.

#define IMG_H 200
#define IMG_W 200
#define IMG_C 512
#define C4 (IMG_C / 4)   // 128 float4 slots per pixel
#define POOL 7
#define NROI 128
#define PLANES 4         // pixel-lanes per block

typedef float f4v __attribute__((ext_vector_type(4)));

__device__ __forceinline__ float4 max4(float4 a, float4 b) {
    return make_float4(fmaxf(a.x, b.x), fmaxf(a.y, b.y),
                       fmaxf(a.z, b.z), fmaxf(a.w, b.w));
}

__global__ __launch_bounds__(PLANES * 128, 8) void roi_pool_kernel(
    const float* __restrict__ img,
    const float* __restrict__ rois,
    float* __restrict__ out)
{
    const int bin = blockIdx.x % (POOL * POOL);
    const int roi = blockIdx.x / (POOL * POOL);
    const int jy = bin / POOL;
    const int ix = bin % POOL;

    const float rx = rois[roi * 4 + 0];
    const float ry = rois[roi * 4 + 1];
    const float rw = rois[roi * 4 + 2];
    const float rh = rois[roi * 4 + 3];

    // Strict fp32, no contraction: s = w/P; b[k] = int(x + k*s)
    const float sx = __fdiv_rn(rw, 7.0f);
    const float sy = __fdiv_rn(rh, 7.0f);
    const int x1 = (int)__fadd_rn(rx, __fmul_rn((float)ix,       sx));
    const int x2 = (int)__fadd_rn(rx, __fmul_rn((float)(ix + 1), sx));
    const int y1 = (int)__fadd_rn(ry, __fmul_rn((float)jy,       sy));
    const int y2 = (int)__fadd_rn(ry, __fmul_rn((float)(jy + 1), sy));

    const int c4 = threadIdx.x & 127;       // channel quad
    const int p  = threadIdx.x >> 7;        // pixel-lane 0..3
    const float4* __restrict__ img4 = (const float4*)img;

    const int bw = x2 - x1;                 // >= 1 by problem construction
    const int area = bw * (y2 - y1);

    const float4 NEG = make_float4(-INFINITY, -INFINITY, -INFINITY, -INFINITY);
    float4 m = NEG;

    // Lane p handles linearized bin pixels p, p+4, p+8, ... (row-major in bin).
    int dx = p, dy = 0;
    while (dx >= bw) { dx -= bw; ++dy; }    // p<4, cheap init
    #pragma unroll 2
    for (int i = p; i < area; i += PLANES) {
        const size_t px = (size_t)(y1 + dy) * IMG_W + (size_t)(x1 + dx);
        m = max4(m, img4[px * C4 + c4]);
        dx += PLANES;
        while (dx >= bw) { dx -= bw; ++dy; }
    }

    // Cross-lane (p) reduction via LDS. Lanes with no pixels hold -INF
    // (identity for max); lane 0 always has >=1 pixel.
    __shared__ float4 red[PLANES - 1][C4];
    if (p > 0) red[p - 1][c4] = m;
    __syncthreads();
    if (p == 0) {
        m = max4(m, red[0][c4]);
        m = max4(m, red[1][c4]);
        m = max4(m, red[2][c4]);

        float4* __restrict__ out4 = (float4*)out;
        f4v* __restrict__ dst =
            (f4v*)&out4[((size_t)(roi * POOL + jy) * POOL + ix) * C4 + c4];
        __builtin_nontemporal_store(*(const f4v*)&m, dst);
    }
}

extern "C" void kernel_launch(void* const* d_in, const int* in_sizes, int n_in,
                              void* d_out, int out_size, void* d_ws, size_t ws_size,
                              hipStream_t stream) {
    (void)in_sizes; (void)n_in; (void)d_ws; (void)ws_size; (void)out_size;
    const float* img  = (const float*)d_in[0];
    const float* rois = (const float*)d_in[1];
    // d_in[2] is pool_size (=7), hardcoded.
    float* out = (float*)d_out;

    dim3 grid(NROI * POOL * POOL);
    dim3 block(PLANES * 128);
    roi_pool_kernel<<<grid, block, 0, stream>>>(img, rois, out);
}